// Round 3
// baseline (547.790 us; speedup 1.0000x reference)
//
#include <hip/hip_runtime.h>

#define NFEAT 128
#define BCAP 3072   // per-bucket slot capacity (mean 2046, sigma ~45 -> +22 sigma)

// ---------- Wt[k][j] = W[j][k] (64 KB) ----------
__global__ void k_transpose(const float* __restrict__ W, float* __restrict__ Wt) {
    int i = blockIdx.x * 256 + threadIdx.x;
    if (i < NFEAT * NFEAT) {
        int r = i >> 7, c = i & 127;
        Wt[c * NFEAT + r] = W[i];
    }
}

// ---------- z = h @ W^T, s1 = z.w1, s2 = z.w2 ----------
__global__ __launch_bounds__(256) void k_gemm(
    const float* __restrict__ h, const float* __restrict__ Wt,
    const float* __restrict__ attn_w,
    float* __restrict__ z, float* __restrict__ s1, float* __restrict__ s2, int n)
{
    __shared__ float hs[32][NFEAT];
    const int tid = threadIdx.x;
    const int cg = tid & 31;
    const int rg = tid >> 5;
    const int nodeBase = blockIdx.x * 32;

    const float4* h4 = reinterpret_cast<const float4*>(h);
    float4* hs4 = reinterpret_cast<float4*>(&hs[0][0]);
    for (int t = tid; t < 32 * 32; t += 256) {
        int row = t >> 5, c4 = t & 31;
        int nn = nodeBase + row;
        hs4[t] = (nn < n) ? h4[(size_t)nn * 32 + c4] : make_float4(0.f, 0.f, 0.f, 0.f);
    }
    __syncthreads();

    const float4* Wt4 = reinterpret_cast<const float4*>(Wt);
    float acc[4][4];
#pragma unroll
    for (int r = 0; r < 4; ++r)
#pragma unroll
        for (int c = 0; c < 4; ++c) acc[r][c] = 0.f;

    for (int k0 = 0; k0 < NFEAT; k0 += 4) {
        float4 wv[4];
#pragma unroll
        for (int i = 0; i < 4; ++i) wv[i] = Wt4[(size_t)(k0 + i) * 32 + cg];
        float4 hv[4];
#pragma unroll
        for (int r = 0; r < 4; ++r)
            hv[r] = *reinterpret_cast<const float4*>(&hs[rg * 4 + r][k0]);
#pragma unroll
        for (int r = 0; r < 4; ++r) {
            float hk;
#pragma unroll
            for (int i = 0; i < 4; ++i) {
                hk = (i == 0) ? hv[r].x : (i == 1) ? hv[r].y : (i == 2) ? hv[r].z : hv[r].w;
                acc[r][0] += hk * wv[i].x;
                acc[r][1] += hk * wv[i].y;
                acc[r][2] += hk * wv[i].z;
                acc[r][3] += hk * wv[i].w;
            }
        }
    }

    const float4 aw1 = reinterpret_cast<const float4*>(attn_w)[cg];
    const float4 aw2 = reinterpret_cast<const float4*>(attn_w)[cg + 32];
    float4* z4 = reinterpret_cast<float4*>(z);

#pragma unroll
    for (int r = 0; r < 4; ++r) {
        int node = nodeBase + rg * 4 + r;
        bool valid = node < n;
        if (valid)
            z4[(size_t)node * 32 + cg] =
                make_float4(acc[r][0], acc[r][1], acc[r][2], acc[r][3]);
        float p1 = acc[r][0] * aw1.x + acc[r][1] * aw1.y + acc[r][2] * aw1.z + acc[r][3] * aw1.w;
        float p2 = acc[r][0] * aw2.x + acc[r][1] * aw2.y + acc[r][2] * aw2.z + acc[r][3] * aw2.w;
#pragma unroll
        for (int off = 16; off > 0; off >>= 1) {
            p1 += __shfl_xor(p1, off);
            p2 += __shfl_xor(p2, off);
        }
        if (cg == 0 && valid) { s1[node] = p1; s2[node] = p2; }
    }
}

// ---------- phase A: scatter edges into 64-node buckets ----------
// packed word: (dst&63)<<22 | etype<<16 | src   (6+6+16 bits)
__global__ void k_bucket(const int* __restrict__ src, const int* __restrict__ dst,
                         const int* __restrict__ etype,
                         int* __restrict__ bucket_cnt, unsigned int* __restrict__ bucket_store,
                         int e)
{
    int i = blockIdx.x * 256 + threadIdx.x;
    if (i < e) {
        int d = dst[i];
        int b = d >> 6;
        int r = atomicAdd(&bucket_cnt[b], 1);
        if (r < BCAP)
            bucket_store[(size_t)b * BCAP + r] =
                (unsigned int)src[i] | ((unsigned int)etype[i] << 16) | ((unsigned int)(d & 63) << 22);
    }
}

// ---------- exclusive scan of bucket counts (single block) ----------
__global__ __launch_bounds__(256) void k_scan_buckets(const int* __restrict__ bucket_cnt,
                                                      int* __restrict__ bucket_scan,
                                                      int* __restrict__ row_start,
                                                      int n, int nb)
{
    __shared__ int wsum[4];
    const int tid = threadIdx.x;
    const int C = (nb + 255) / 256;   // elems per thread (<=8 assumed)
    const int base_i = tid * C;
    int vals[8];
    int s = 0;
#pragma unroll
    for (int j = 0; j < 8; ++j) {
        int v = 0;
        if (j < C) {
            int idx = base_i + j;
            if (idx < nb) v = min(bucket_cnt[idx], BCAP);
        }
        vals[j] = v; s += v;
    }
    int lane = tid & 63, wave = tid >> 6;
    int x = s;
#pragma unroll
    for (int off = 1; off < 64; off <<= 1) {
        int t = __shfl_up(x, off);
        if (lane >= off) x += t;
    }
    if (lane == 63) wsum[wave] = x;
    __syncthreads();
    int wbase = 0;
    for (int w = 0; w < wave; ++w) wbase += wsum[w];
    int ex = wbase + x - s;   // exclusive prefix for this thread's chunk
#pragma unroll
    for (int j = 0; j < 8; ++j) {
        if (j < C) {
            int idx = base_i + j;
            if (idx < nb) bucket_scan[idx] = ex;
            ex += vals[j];
        }
    }
    if (tid == 255) row_start[n] = ex;   // total == e
}

// ---------- phase B: per-bucket local sort -> CSR + row_start ----------
__global__ __launch_bounds__(256) void k_place(
    const unsigned int* __restrict__ bucket_store, const int* __restrict__ bucket_cnt,
    const int* __restrict__ bucket_scan,
    int* __restrict__ row_start, unsigned int* __restrict__ edge_list, int n)
{
    __shared__ unsigned int est[BCAP];
    __shared__ int cnt64[64];
    const int b = blockIdx.x;
    const int tid = threadIdx.x;
    const int cnt = min(bucket_cnt[b], BCAP);
    const int base = bucket_scan[b];

    if (tid < 64) cnt64[tid] = 0;
    for (int j = tid; j < cnt; j += 256)
        est[j] = bucket_store[(size_t)b * BCAP + j];
    __syncthreads();
    for (int j = tid; j < cnt; j += 256)
        atomicAdd(&cnt64[est[j] >> 22], 1);
    __syncthreads();
    if (tid < 64) {   // wave 0: exclusive scan of the 64 node counts
        int v = cnt64[tid];
        int x = v;
#pragma unroll
        for (int off = 1; off < 64; off <<= 1) {
            int t = __shfl_up(x, off);
            if (tid >= off) x += t;
        }
        int node = (b << 6) + tid;
        if (node < n) row_start[node] = base + x - v;
        cnt64[tid] = x - v;   // becomes the cursor
    }
    __syncthreads();
    for (int j = tid; j < cnt; j += 256) {
        unsigned int pk = est[j];
        int pos = base + atomicAdd(&cnt64[pk >> 22], 1);
        edge_list[pos] = pk & 0x3FFFFFu;   // keep etype<<16 | src
    }
}

// ---------- per-node softmax + weighted aggregation; 1 wave = 1 node ----------
__global__ __launch_bounds__(256) void k_aggregate(
    const float* __restrict__ z, const float* __restrict__ s1, const float* __restrict__ s2,
    const float* __restrict__ rel_emb, const float* __restrict__ bias,
    const int* __restrict__ row_start, const unsigned int* __restrict__ edge_list,
    float* __restrict__ out, int n)
{
    __shared__ uint2 lds_ws[4][64];
    const int wv   = threadIdx.x >> 6;
    const int lane = threadIdx.x & 63;
    const int node = blockIdx.x * 4 + wv;
    if (node >= n) return;

    const int beg = row_start[node];
    const int end = row_start[node + 1];
    const int deg = end - beg;
    const int half = lane >> 5;
    const int q    = lane & 31;

    float4 acc = make_float4(0.f, 0.f, 0.f, 0.f);
    const float4* z4 = reinterpret_cast<const float4*>(z);

    if (deg > 0) {
        const float s2n = s2[node];

        if (deg <= 64) {
            unsigned int pk = 0;
            float ev = -3.4e38f;
            const bool has = lane < deg;
            if (has) {
                pk = edge_list[beg + lane];
                ev = s1[pk & 0xFFFFu] + s2n;
                ev = ev > 0.f ? ev : 0.01f * ev;
            }
            float m = ev;
#pragma unroll
            for (int off = 32; off > 0; off >>= 1)
                m = fmaxf(m, __shfl_xor(m, off));
            float p = has ? __expf(ev - m) : 0.f;
            float den = p;
#pragma unroll
            for (int off = 32; off > 0; off >>= 1)
                den += __shfl_xor(den, off);
            const float inv = 1.f / den;
            if (has)
                lds_ws[wv][lane] = make_uint2(pk & 0xFFFFu,
                                              __float_as_uint(rel_emb[pk >> 16] * p * inv));
#pragma unroll 2
            for (int j = half; j < deg; j += 2) {
                uint2 t = lds_ws[wv][j];
                float w = __uint_as_float(t.y);
                float4 zr = z4[(size_t)t.x * 32 + q];
                acc.x += w * zr.x; acc.y += w * zr.y;
                acc.z += w * zr.z; acc.w += w * zr.w;
            }
        } else {
            float mymax = -3.4e38f;
            for (int k = beg + lane; k < end; k += 64) {
                unsigned int pk = edge_list[k];
                float ev = s1[pk & 0xFFFFu] + s2n;
                ev = ev > 0.f ? ev : 0.01f * ev;
                mymax = fmaxf(mymax, ev);
            }
#pragma unroll
            for (int off = 32; off > 0; off >>= 1)
                mymax = fmaxf(mymax, __shfl_xor(mymax, off));
            float mysum = 0.f;
            for (int k = beg + lane; k < end; k += 64) {
                unsigned int pk = edge_list[k];
                float ev = s1[pk & 0xFFFFu] + s2n;
                ev = ev > 0.f ? ev : 0.01f * ev;
                mysum += __expf(ev - mymax);
            }
#pragma unroll
            for (int off = 32; off > 0; off >>= 1)
                mysum += __shfl_xor(mysum, off);
            const float inv = 1.f / mysum;

            for (int cb = beg; cb < end; cb += 64) {
                int k = cb + lane;
                if (k < end) {
                    unsigned int pk = edge_list[k];
                    int s = pk & 0xFFFFu;
                    float ev = s1[s] + s2n;
                    ev = ev > 0.f ? ev : 0.01f * ev;
                    lds_ws[wv][lane] = make_uint2((unsigned)s,
                        __float_as_uint(rel_emb[pk >> 16] * __expf(ev - mymax) * inv));
                }
                int cnt = min(64, end - cb);
#pragma unroll 2
                for (int j = half; j < cnt; j += 2) {
                    uint2 t = lds_ws[wv][j];
                    float w = __uint_as_float(t.y);
                    float4 zr = z4[(size_t)t.x * 32 + q];
                    acc.x += w * zr.x; acc.y += w * zr.y;
                    acc.z += w * zr.z; acc.w += w * zr.w;
                }
            }
        }
        acc.x += __shfl_xor(acc.x, 32);
        acc.y += __shfl_xor(acc.y, 32);
        acc.z += __shfl_xor(acc.z, 32);
        acc.w += __shfl_xor(acc.w, 32);
    }

    if (half == 0) {
        float4 b = reinterpret_cast<const float4*>(bias)[q];
        reinterpret_cast<float4*>(out)[(size_t)node * 32 + q] =
            make_float4(acc.x + b.x, acc.y + b.y, acc.z + b.z, acc.w + b.w);
    }
}

extern "C" void kernel_launch(void* const* d_in, const int* in_sizes, int n_in,
                              void* d_out, int out_size, void* d_ws, size_t ws_size,
                              hipStream_t stream) {
    const float* h      = (const float*)d_in[0];
    const float* W      = (const float*)d_in[1];
    const float* attn_w = (const float*)d_in[2];
    const float* rel    = (const float*)d_in[3];
    const float* bias   = (const float*)d_in[4];
    const int*   src    = (const int*)d_in[5];
    const int*   dst    = (const int*)d_in[6];
    const int*   etype  = (const int*)d_in[7];
    const int n = in_sizes[0] / NFEAT;   // 50000
    const int e = in_sizes[5];           // 1600000
    const int nb = (n + 63) / 64;        // 782 buckets
    float* out = (float*)d_out;

    // workspace layout
    char* p = (char*)d_ws;
    float* z  = (float*)p;                 p += (size_t)n * NFEAT * 4;
    float* s1 = (float*)p;                 p += (size_t)n * 4;
    float* s2 = (float*)p;                 p += (size_t)n * 4;
    float* Wt = (float*)p;                 p += (size_t)NFEAT * NFEAT * 4;
    int* row_start = (int*)p;              p += (size_t)(n + 1) * 4;
    int* bucket_cnt  = (int*)p;            p += (size_t)nb * 4;
    int* bucket_scan = (int*)p;            p += (size_t)nb * 4;
    unsigned int* edge_list = (unsigned int*)p;     p += (size_t)e * 4;
    unsigned int* bucket_store = (unsigned int*)p;  p += (size_t)nb * BCAP * 4;

    hipMemsetAsync(bucket_cnt, 0, (size_t)nb * sizeof(int), stream);

    k_transpose<<<(NFEAT * NFEAT + 255) / 256, 256, 0, stream>>>(W, Wt);
    k_gemm<<<(n + 31) / 32, 256, 0, stream>>>(h, Wt, attn_w, z, s1, s2, n);
    k_bucket<<<(e + 255) / 256, 256, 0, stream>>>(src, dst, etype, bucket_cnt, bucket_store, e);
    k_scan_buckets<<<1, 256, 0, stream>>>(bucket_cnt, bucket_scan, row_start, n, nb);
    k_place<<<nb, 256, 0, stream>>>(bucket_store, bucket_cnt, bucket_scan, row_start, edge_list, n);
    k_aggregate<<<(n + 3) / 4, 256, 0, stream>>>(z, s1, s2, rel, bias, row_start, edge_list, out, n);
}

// Round 4
// 194.677 us; speedup vs baseline: 2.8138x; 2.8138x over previous
//
#include <hip/hip_runtime.h>

#define NFEAT 128
#define NBUK_MAX 1024   // actual buckets = ceil(50000/64) = 782
#define HB 256          // blocks for hist/scatter passes
#define BCAP_L 4096     // k_place LDS edge capacity (mean 2046, sigma ~45)

// ---------- Wt[k][j] = W[j][k] (64 KB) ----------
__global__ void k_transpose(const float* __restrict__ W, float* __restrict__ Wt) {
    int i = blockIdx.x * 256 + threadIdx.x;
    if (i < NFEAT * NFEAT) {
        int r = i >> 7, c = i & 127;
        Wt[c * NFEAT + r] = W[i];
    }
}

// ---------- z = h @ W^T, s1 = z.w1, s2 = z.w2 ----------
__global__ __launch_bounds__(256) void k_gemm(
    const float* __restrict__ h, const float* __restrict__ Wt,
    const float* __restrict__ attn_w,
    float* __restrict__ z, float* __restrict__ s1, float* __restrict__ s2, int n)
{
    __shared__ float hs[32][NFEAT];
    const int tid = threadIdx.x;
    const int cg = tid & 31;
    const int rg = tid >> 5;
    const int nodeBase = blockIdx.x * 32;

    const float4* h4 = reinterpret_cast<const float4*>(h);
    float4* hs4 = reinterpret_cast<float4*>(&hs[0][0]);
    for (int t = tid; t < 32 * 32; t += 256) {
        int row = t >> 5, c4 = t & 31;
        int nn = nodeBase + row;
        hs4[t] = (nn < n) ? h4[(size_t)nn * 32 + c4] : make_float4(0.f, 0.f, 0.f, 0.f);
    }
    __syncthreads();

    const float4* Wt4 = reinterpret_cast<const float4*>(Wt);
    float acc[4][4];
#pragma unroll
    for (int r = 0; r < 4; ++r)
#pragma unroll
        for (int c = 0; c < 4; ++c) acc[r][c] = 0.f;

    for (int k0 = 0; k0 < NFEAT; k0 += 4) {
        float4 wv[4];
#pragma unroll
        for (int i = 0; i < 4; ++i) wv[i] = Wt4[(size_t)(k0 + i) * 32 + cg];
        float4 hv[4];
#pragma unroll
        for (int r = 0; r < 4; ++r)
            hv[r] = *reinterpret_cast<const float4*>(&hs[rg * 4 + r][k0]);
#pragma unroll
        for (int r = 0; r < 4; ++r) {
            float hk;
#pragma unroll
            for (int i = 0; i < 4; ++i) {
                hk = (i == 0) ? hv[r].x : (i == 1) ? hv[r].y : (i == 2) ? hv[r].z : hv[r].w;
                acc[r][0] += hk * wv[i].x;
                acc[r][1] += hk * wv[i].y;
                acc[r][2] += hk * wv[i].z;
                acc[r][3] += hk * wv[i].w;
            }
        }
    }

    const float4 aw1 = reinterpret_cast<const float4*>(attn_w)[cg];
    const float4 aw2 = reinterpret_cast<const float4*>(attn_w)[cg + 32];
    float4* z4 = reinterpret_cast<float4*>(z);

#pragma unroll
    for (int r = 0; r < 4; ++r) {
        int node = nodeBase + rg * 4 + r;
        bool valid = node < n;
        if (valid)
            z4[(size_t)node * 32 + cg] =
                make_float4(acc[r][0], acc[r][1], acc[r][2], acc[r][3]);
        float p1 = acc[r][0] * aw1.x + acc[r][1] * aw1.y + acc[r][2] * aw1.z + acc[r][3] * aw1.w;
        float p2 = acc[r][0] * aw2.x + acc[r][1] * aw2.y + acc[r][2] * aw2.z + acc[r][3] * aw2.w;
#pragma unroll
        for (int off = 16; off > 0; off >>= 1) {
            p1 += __shfl_xor(p1, off);
            p2 += __shfl_xor(p2, off);
        }
        if (cg == 0 && valid) { s1[node] = p1; s2[node] = p2; }
    }
}

// ---------- pass 1: per-block LDS histogram over coarse buckets ----------
__global__ __launch_bounds__(256) void k_hist(const int* __restrict__ dst,
                                              int* __restrict__ hist,
                                              int e, int nbuk, int epb)
{
    __shared__ int lh[NBUK_MAX];
    const int b = blockIdx.x, tid = threadIdx.x;
    for (int k = tid; k < nbuk; k += 256) lh[k] = 0;
    __syncthreads();
    const int beg = b * epb, end = min(e, beg + epb);
    for (int i = beg + tid; i < end; i += 256)
        atomicAdd(&lh[dst[i] >> 6], 1);
    __syncthreads();
    for (int k = tid; k < nbuk; k += 256)
        hist[b * nbuk + k] = lh[k];
}

// ---------- pass 2a: per-bucket exclusive scan over blocks ----------
__global__ __launch_bounds__(256) void k_scan_blocks(const int* __restrict__ hist,
                                                     int* __restrict__ base,
                                                     int* __restrict__ bucket_tot, int nbuk)
{
    __shared__ int wsum[4];
    const int k = blockIdx.x, tid = threadIdx.x;
    int v = hist[tid * nbuk + k];
    int lane = tid & 63, wave = tid >> 6;
    int x = v;
#pragma unroll
    for (int off = 1; off < 64; off <<= 1) {
        int t = __shfl_up(x, off);
        if (lane >= off) x += t;
    }
    if (lane == 63) wsum[wave] = x;
    __syncthreads();
    int wb = 0;
    for (int w = 0; w < wave; ++w) wb += wsum[w];
    base[tid * nbuk + k] = wb + x - v;
    if (tid == 255) bucket_tot[k] = wb + x;
}

// ---------- pass 2b: exclusive scan of bucket totals (single block) ----------
__global__ __launch_bounds__(256) void k_scan_buckets(const int* __restrict__ bucket_tot,
                                                      int* __restrict__ bucket_base,
                                                      int* __restrict__ row_start,
                                                      int n, int nbuk)
{
    __shared__ int wsum[4];
    const int tid = threadIdx.x;
    const int C = (nbuk + 255) / 256;   // <= 4
    const int base_i = tid * C;
    int vals[8];
    int s = 0;
#pragma unroll
    for (int j = 0; j < 8; ++j) {
        int v = 0;
        if (j < C) {
            int idx = base_i + j;
            if (idx < nbuk) v = bucket_tot[idx];
        }
        vals[j] = v; s += v;
    }
    int lane = tid & 63, wave = tid >> 6;
    int x = s;
#pragma unroll
    for (int off = 1; off < 64; off <<= 1) {
        int t = __shfl_up(x, off);
        if (lane >= off) x += t;
    }
    if (lane == 63) wsum[wave] = x;
    __syncthreads();
    int wb = 0;
    for (int w = 0; w < wave; ++w) wb += wsum[w];
    int ex = wb + x - s;
#pragma unroll
    for (int j = 0; j < 8; ++j) {
        if (j < C) {
            int idx = base_i + j;
            if (idx < nbuk) bucket_base[idx] = ex;
            ex += vals[j];
        }
    }
    if (tid == 255) row_start[n] = ex;   // == e
}

// ---------- pass 3: deterministic scatter into coarse-sorted store ----------
// packed word: (dst&63)<<22 | etype<<16 | src
__global__ __launch_bounds__(256) void k_sctr(
    const int* __restrict__ src, const int* __restrict__ dst, const int* __restrict__ etype,
    const int* __restrict__ base, const int* __restrict__ bucket_base,
    unsigned int* __restrict__ bucket_store, int e, int nbuk, int epb)
{
    __shared__ int cur[NBUK_MAX];
    const int b = blockIdx.x, tid = threadIdx.x;
    for (int k = tid; k < nbuk; k += 256)
        cur[k] = base[b * nbuk + k] + bucket_base[k];
    __syncthreads();
    const int beg = b * epb, end = min(e, beg + epb);
    for (int i = beg + tid; i < end; i += 256) {
        int d = dst[i];
        int pos = atomicAdd(&cur[d >> 6], 1);
        bucket_store[pos] =
            (unsigned int)src[i] | ((unsigned int)etype[i] << 16) | ((unsigned int)(d & 63) << 22);
    }
}

// ---------- pass 4: per-bucket local sort -> CSR + row_start ----------
__global__ __launch_bounds__(256) void k_place(
    const unsigned int* __restrict__ bucket_store, const int* __restrict__ bucket_tot,
    const int* __restrict__ bucket_base,
    int* __restrict__ row_start, unsigned int* __restrict__ edge_list, int n)
{
    __shared__ unsigned int est[BCAP_L];
    __shared__ int cnt64[64];
    const int b = blockIdx.x;
    const int tid = threadIdx.x;
    const int cnt = min(bucket_tot[b], BCAP_L);
    const int base = bucket_base[b];

    if (tid < 64) cnt64[tid] = 0;
    for (int j = tid; j < cnt; j += 256)
        est[j] = bucket_store[(size_t)base + j];
    __syncthreads();
    for (int j = tid; j < cnt; j += 256)
        atomicAdd(&cnt64[est[j] >> 22], 1);
    __syncthreads();
    if (tid < 64) {
        int v = cnt64[tid];
        int x = v;
#pragma unroll
        for (int off = 1; off < 64; off <<= 1) {
            int t = __shfl_up(x, off);
            if (tid >= off) x += t;
        }
        int node = (b << 6) + tid;
        if (node < n) row_start[node] = base + x - v;
        cnt64[tid] = x - v;
    }
    __syncthreads();
    for (int j = tid; j < cnt; j += 256) {
        unsigned int pk = est[j];
        int pos = base + atomicAdd(&cnt64[pk >> 22], 1);
        edge_list[pos] = pk & 0x3FFFFFu;
    }
}

// ---------- per-node softmax + weighted aggregation; 1 wave = 1 node ----------
__global__ __launch_bounds__(256) void k_aggregate(
    const float* __restrict__ z, const float* __restrict__ s1, const float* __restrict__ s2,
    const float* __restrict__ rel_emb, const float* __restrict__ bias,
    const int* __restrict__ row_start, const unsigned int* __restrict__ edge_list,
    float* __restrict__ out, int n)
{
    __shared__ uint2 lds_ws[4][64];
    const int wv   = threadIdx.x >> 6;
    const int lane = threadIdx.x & 63;
    const int node = blockIdx.x * 4 + wv;
    if (node >= n) return;

    const int beg = row_start[node];
    const int end = row_start[node + 1];
    const int deg = end - beg;
    const int half = lane >> 5;
    const int q    = lane & 31;

    float4 acc = make_float4(0.f, 0.f, 0.f, 0.f);
    const float4* z4 = reinterpret_cast<const float4*>(z);

    if (deg > 0) {
        const float s2n = s2[node];

        if (deg <= 64) {
            unsigned int pk = 0;
            float ev = -3.4e38f;
            const bool has = lane < deg;
            if (has) {
                pk = edge_list[beg + lane];
                ev = s1[pk & 0xFFFFu] + s2n;
                ev = ev > 0.f ? ev : 0.01f * ev;
            }
            float m = ev;
#pragma unroll
            for (int off = 32; off > 0; off >>= 1)
                m = fmaxf(m, __shfl_xor(m, off));
            float p = has ? __expf(ev - m) : 0.f;
            float den = p;
#pragma unroll
            for (int off = 32; off > 0; off >>= 1)
                den += __shfl_xor(den, off);
            const float inv = 1.f / den;
            if (has)
                lds_ws[wv][lane] = make_uint2(pk & 0xFFFFu,
                                              __float_as_uint(rel_emb[pk >> 16] * p * inv));
#pragma unroll 2
            for (int j = half; j < deg; j += 2) {
                uint2 t = lds_ws[wv][j];
                float w = __uint_as_float(t.y);
                float4 zr = z4[(size_t)t.x * 32 + q];
                acc.x += w * zr.x; acc.y += w * zr.y;
                acc.z += w * zr.z; acc.w += w * zr.w;
            }
        } else {
            float mymax = -3.4e38f;
            for (int k = beg + lane; k < end; k += 64) {
                unsigned int pk = edge_list[k];
                float ev = s1[pk & 0xFFFFu] + s2n;
                ev = ev > 0.f ? ev : 0.01f * ev;
                mymax = fmaxf(mymax, ev);
            }
#pragma unroll
            for (int off = 32; off > 0; off >>= 1)
                mymax = fmaxf(mymax, __shfl_xor(mymax, off));
            float mysum = 0.f;
            for (int k = beg + lane; k < end; k += 64) {
                unsigned int pk = edge_list[k];
                float ev = s1[pk & 0xFFFFu] + s2n;
                ev = ev > 0.f ? ev : 0.01f * ev;
                mysum += __expf(ev - mymax);
            }
#pragma unroll
            for (int off = 32; off > 0; off >>= 1)
                mysum += __shfl_xor(mysum, off);
            const float inv = 1.f / mysum;

            for (int cb = beg; cb < end; cb += 64) {
                int k = cb + lane;
                if (k < end) {
                    unsigned int pk = edge_list[k];
                    int s = pk & 0xFFFFu;
                    float ev = s1[s] + s2n;
                    ev = ev > 0.f ? ev : 0.01f * ev;
                    lds_ws[wv][lane] = make_uint2((unsigned)s,
                        __float_as_uint(rel_emb[pk >> 16] * __expf(ev - mymax) * inv));
                }
                int cnt = min(64, end - cb);
#pragma unroll 2
                for (int j = half; j < cnt; j += 2) {
                    uint2 t = lds_ws[wv][j];
                    float w = __uint_as_float(t.y);
                    float4 zr = z4[(size_t)t.x * 32 + q];
                    acc.x += w * zr.x; acc.y += w * zr.y;
                    acc.z += w * zr.z; acc.w += w * zr.w;
                }
            }
        }
        acc.x += __shfl_xor(acc.x, 32);
        acc.y += __shfl_xor(acc.y, 32);
        acc.z += __shfl_xor(acc.z, 32);
        acc.w += __shfl_xor(acc.w, 32);
    }

    if (half == 0) {
        float4 b = reinterpret_cast<const float4*>(bias)[q];
        reinterpret_cast<float4*>(out)[(size_t)node * 32 + q] =
            make_float4(acc.x + b.x, acc.y + b.y, acc.z + b.z, acc.w + b.w);
    }
}

extern "C" void kernel_launch(void* const* d_in, const int* in_sizes, int n_in,
                              void* d_out, int out_size, void* d_ws, size_t ws_size,
                              hipStream_t stream) {
    const float* h      = (const float*)d_in[0];
    const float* W      = (const float*)d_in[1];
    const float* attn_w = (const float*)d_in[2];
    const float* rel    = (const float*)d_in[3];
    const float* bias   = (const float*)d_in[4];
    const int*   src    = (const int*)d_in[5];
    const int*   dst    = (const int*)d_in[6];
    const int*   etype  = (const int*)d_in[7];
    const int n = in_sizes[0] / NFEAT;   // 50000
    const int e = in_sizes[5];           // 1600000
    const int nbuk = (n + 63) / 64;      // 782
    const int epb = (e + HB - 1) / HB;   // 6250
    float* out = (float*)d_out;

    // workspace layout
    char* p = (char*)d_ws;
    float* z  = (float*)p;                 p += (size_t)n * NFEAT * 4;
    float* s1 = (float*)p;                 p += (size_t)n * 4;
    float* s2 = (float*)p;                 p += (size_t)n * 4;
    float* Wt = (float*)p;                 p += (size_t)NFEAT * NFEAT * 4;
    int* row_start = (int*)p;              p += (size_t)(n + 1) * 4;
    int* hist       = (int*)p;             p += (size_t)HB * nbuk * 4;
    int* base       = (int*)p;             p += (size_t)HB * nbuk * 4;
    int* bucket_tot = (int*)p;             p += (size_t)nbuk * 4;
    int* bucket_base= (int*)p;             p += (size_t)nbuk * 4;
    unsigned int* edge_list    = (unsigned int*)p;  p += (size_t)e * 4;
    unsigned int* bucket_store = (unsigned int*)p;  p += (size_t)e * 4;

    k_transpose<<<(NFEAT * NFEAT + 255) / 256, 256, 0, stream>>>(W, Wt);
    k_gemm<<<(n + 31) / 32, 256, 0, stream>>>(h, Wt, attn_w, z, s1, s2, n);
    k_hist<<<HB, 256, 0, stream>>>(dst, hist, e, nbuk, epb);
    k_scan_blocks<<<nbuk, 256, 0, stream>>>(hist, base, bucket_tot, nbuk);
    k_scan_buckets<<<1, 256, 0, stream>>>(bucket_tot, bucket_base, row_start, n, nbuk);
    k_sctr<<<HB, 256, 0, stream>>>(src, dst, etype, base, bucket_base, bucket_store, e, nbuk, epb);
    k_place<<<nbuk, 256, 0, stream>>>(bucket_store, bucket_tot, bucket_base, row_start, edge_list, n);
    k_aggregate<<<(n + 3) / 4, 256, 0, stream>>>(z, s1, s2, rel, bias, row_start, edge_list, out, n);
}

// Round 5
// 147.692 us; speedup vs baseline: 3.7090x; 1.3181x over previous
//
#include <hip/hip_runtime.h>
#include <hip/hip_fp16.h>

#define NFEAT 128
#define NBUK_MAX 1024   // actual buckets = ceil(50000/64) = 782
#define HB 256          // blocks for hist/scatter passes
#define BCAP_L 4096     // k_place LDS edge capacity (mean 2046, sigma ~45)

// ---------- Wt[k][j] = W[j][k] (64 KB) ----------
__global__ void k_transpose(const float* __restrict__ W, float* __restrict__ Wt) {
    int i = blockIdx.x * 256 + threadIdx.x;
    if (i < NFEAT * NFEAT) {
        int r = i >> 7, c = i & 127;
        Wt[c * NFEAT + r] = W[i];
    }
}

// ---------- z(fp16) = h @ W^T, s1 = z.w1, s2 = z.w2 (scores from fp32 acc) ----------
__global__ __launch_bounds__(256) void k_gemm(
    const float* __restrict__ h, const float* __restrict__ Wt,
    const float* __restrict__ attn_w,
    __half* __restrict__ zh, float* __restrict__ s1, float* __restrict__ s2, int n)
{
    __shared__ float hs[32][NFEAT];
    const int tid = threadIdx.x;
    const int cg = tid & 31;
    const int rg = tid >> 5;
    const int nodeBase = blockIdx.x * 32;

    const float4* h4 = reinterpret_cast<const float4*>(h);
    float4* hs4 = reinterpret_cast<float4*>(&hs[0][0]);
    for (int t = tid; t < 32 * 32; t += 256) {
        int row = t >> 5, c4 = t & 31;
        int nn = nodeBase + row;
        hs4[t] = (nn < n) ? h4[(size_t)nn * 32 + c4] : make_float4(0.f, 0.f, 0.f, 0.f);
    }
    __syncthreads();

    const float4* Wt4 = reinterpret_cast<const float4*>(Wt);
    float acc[4][4];
#pragma unroll
    for (int r = 0; r < 4; ++r)
#pragma unroll
        for (int c = 0; c < 4; ++c) acc[r][c] = 0.f;

    for (int k0 = 0; k0 < NFEAT; k0 += 4) {
        float4 wv[4];
#pragma unroll
        for (int i = 0; i < 4; ++i) wv[i] = Wt4[(size_t)(k0 + i) * 32 + cg];
        float4 hv[4];
#pragma unroll
        for (int r = 0; r < 4; ++r)
            hv[r] = *reinterpret_cast<const float4*>(&hs[rg * 4 + r][k0]);
#pragma unroll
        for (int r = 0; r < 4; ++r) {
            float hk;
#pragma unroll
            for (int i = 0; i < 4; ++i) {
                hk = (i == 0) ? hv[r].x : (i == 1) ? hv[r].y : (i == 2) ? hv[r].z : hv[r].w;
                acc[r][0] += hk * wv[i].x;
                acc[r][1] += hk * wv[i].y;
                acc[r][2] += hk * wv[i].z;
                acc[r][3] += hk * wv[i].w;
            }
        }
    }

    const float4 aw1 = reinterpret_cast<const float4*>(attn_w)[cg];
    const float4 aw2 = reinterpret_cast<const float4*>(attn_w)[cg + 32];
    uint2* zh2 = reinterpret_cast<uint2*>(zh);

#pragma unroll
    for (int r = 0; r < 4; ++r) {
        int node = nodeBase + rg * 4 + r;
        bool valid = node < n;
        if (valid) {
            __half2 a01 = __floats2half2_rn(acc[r][0], acc[r][1]);
            __half2 a23 = __floats2half2_rn(acc[r][2], acc[r][3]);
            uint2 pk;
            pk.x = *reinterpret_cast<unsigned*>(&a01);
            pk.y = *reinterpret_cast<unsigned*>(&a23);
            zh2[(size_t)node * 32 + cg] = pk;
        }
        float p1 = acc[r][0] * aw1.x + acc[r][1] * aw1.y + acc[r][2] * aw1.z + acc[r][3] * aw1.w;
        float p2 = acc[r][0] * aw2.x + acc[r][1] * aw2.y + acc[r][2] * aw2.z + acc[r][3] * aw2.w;
#pragma unroll
        for (int off = 16; off > 0; off >>= 1) {
            p1 += __shfl_xor(p1, off);
            p2 += __shfl_xor(p2, off);
        }
        if (cg == 0 && valid) { s1[node] = p1; s2[node] = p2; }
    }
}

// ---------- pass 1: per-block LDS histogram over coarse buckets ----------
__global__ __launch_bounds__(256) void k_hist(const int* __restrict__ dst,
                                              int* __restrict__ hist,
                                              int e, int nbuk, int epb)
{
    __shared__ int lh[NBUK_MAX];
    const int b = blockIdx.x, tid = threadIdx.x;
    for (int k = tid; k < nbuk; k += 256) lh[k] = 0;
    __syncthreads();
    const int beg = b * epb, end = min(e, beg + epb);
    for (int i = beg + tid; i < end; i += 256)
        atomicAdd(&lh[dst[i] >> 6], 1);
    __syncthreads();
    for (int k = tid; k < nbuk; k += 256)
        hist[b * nbuk + k] = lh[k];
}

// ---------- pass 2a: per-bucket exclusive scan over blocks ----------
__global__ __launch_bounds__(256) void k_scan_blocks(const int* __restrict__ hist,
                                                     int* __restrict__ base,
                                                     int* __restrict__ bucket_tot, int nbuk)
{
    __shared__ int wsum[4];
    const int k = blockIdx.x, tid = threadIdx.x;
    int v = hist[tid * nbuk + k];
    int lane = tid & 63, wave = tid >> 6;
    int x = v;
#pragma unroll
    for (int off = 1; off < 64; off <<= 1) {
        int t = __shfl_up(x, off);
        if (lane >= off) x += t;
    }
    if (lane == 63) wsum[wave] = x;
    __syncthreads();
    int wb = 0;
    for (int w = 0; w < wave; ++w) wb += wsum[w];
    base[tid * nbuk + k] = wb + x - v;
    if (tid == 255) bucket_tot[k] = wb + x;
}

// ---------- pass 2b: exclusive scan of bucket totals (single block) ----------
__global__ __launch_bounds__(256) void k_scan_buckets(const int* __restrict__ bucket_tot,
                                                      int* __restrict__ bucket_base,
                                                      int* __restrict__ row_start,
                                                      int n, int nbuk)
{
    __shared__ int wsum[4];
    const int tid = threadIdx.x;
    const int C = (nbuk + 255) / 256;   // <= 4
    const int base_i = tid * C;
    int vals[8];
    int s = 0;
#pragma unroll
    for (int j = 0; j < 8; ++j) {
        int v = 0;
        if (j < C) {
            int idx = base_i + j;
            if (idx < nbuk) v = bucket_tot[idx];
        }
        vals[j] = v; s += v;
    }
    int lane = tid & 63, wave = tid >> 6;
    int x = s;
#pragma unroll
    for (int off = 1; off < 64; off <<= 1) {
        int t = __shfl_up(x, off);
        if (lane >= off) x += t;
    }
    if (lane == 63) wsum[wave] = x;
    __syncthreads();
    int wb = 0;
    for (int w = 0; w < wave; ++w) wb += wsum[w];
    int ex = wb + x - s;
#pragma unroll
    for (int j = 0; j < 8; ++j) {
        if (j < C) {
            int idx = base_i + j;
            if (idx < nbuk) bucket_base[idx] = ex;
            ex += vals[j];
        }
    }
    if (tid == 255) row_start[n] = ex;   // == e
}

// ---------- pass 3: deterministic scatter into coarse-sorted store ----------
// packed word: (dst&63)<<22 | etype<<16 | src
__global__ __launch_bounds__(256) void k_sctr(
    const int* __restrict__ src, const int* __restrict__ dst, const int* __restrict__ etype,
    const int* __restrict__ base, const int* __restrict__ bucket_base,
    unsigned int* __restrict__ bucket_store, int e, int nbuk, int epb)
{
    __shared__ int cur[NBUK_MAX];
    const int b = blockIdx.x, tid = threadIdx.x;
    for (int k = tid; k < nbuk; k += 256)
        cur[k] = base[b * nbuk + k] + bucket_base[k];
    __syncthreads();
    const int beg = b * epb, end = min(e, beg + epb);
    for (int i = beg + tid; i < end; i += 256) {
        int d = dst[i];
        int pos = atomicAdd(&cur[d >> 6], 1);
        bucket_store[pos] =
            (unsigned int)src[i] | ((unsigned int)etype[i] << 16) | ((unsigned int)(d & 63) << 22);
    }
}

// ---------- pass 4: per-bucket local sort -> CSR + row_start ----------
__global__ __launch_bounds__(256) void k_place(
    const unsigned int* __restrict__ bucket_store, const int* __restrict__ bucket_tot,
    const int* __restrict__ bucket_base,
    int* __restrict__ row_start, unsigned int* __restrict__ edge_list, int n)
{
    __shared__ unsigned int est[BCAP_L];
    __shared__ int cnt64[64];
    const int b = blockIdx.x;
    const int tid = threadIdx.x;
    const int cnt = min(bucket_tot[b], BCAP_L);
    const int base = bucket_base[b];

    if (tid < 64) cnt64[tid] = 0;
    for (int j = tid; j < cnt; j += 256)
        est[j] = bucket_store[(size_t)base + j];
    __syncthreads();
    for (int j = tid; j < cnt; j += 256)
        atomicAdd(&cnt64[est[j] >> 22], 1);
    __syncthreads();
    if (tid < 64) {
        int v = cnt64[tid];
        int x = v;
#pragma unroll
        for (int off = 1; off < 64; off <<= 1) {
            int t = __shfl_up(x, off);
            if (tid >= off) x += t;
        }
        int node = (b << 6) + tid;
        if (node < n) row_start[node] = base + x - v;
        cnt64[tid] = x - v;
    }
    __syncthreads();
    for (int j = tid; j < cnt; j += 256) {
        unsigned int pk = est[j];
        int pos = base + atomicAdd(&cnt64[pk >> 22], 1);
        edge_list[pos] = pk & 0x3FFFFFu;
    }
}

// ---------- per-node softmax + weighted aggregation; 1 wave = 1 node ----------
// gather: 4 edges/iter, quarter-wave (16 lanes) x uint4 (8 halfs) per edge
__global__ __launch_bounds__(256) void k_aggregate(
    const __half* __restrict__ zh, const float* __restrict__ s1, const float* __restrict__ s2,
    const float* __restrict__ rel_emb, const float* __restrict__ bias,
    const int* __restrict__ row_start, const unsigned int* __restrict__ edge_list,
    float* __restrict__ out, int n)
{
    __shared__ uint2 lds_ws[4][64];
    const int wv   = threadIdx.x >> 6;
    const int lane = threadIdx.x & 63;
    const int node = blockIdx.x * 4 + wv;
    if (node >= n) return;

    const int beg = row_start[node];
    const int end = row_start[node + 1];
    const int deg = end - beg;
    const int quad = lane >> 4;   // which edge of the group of 4
    const int q    = lane & 15;   // 8-half chunk within the 128-feat row

    float acc[8];
#pragma unroll
    for (int j = 0; j < 8; ++j) acc[j] = 0.f;
    const uint4* z4 = reinterpret_cast<const uint4*>(zh);

    if (deg > 0) {
        const float s2n = s2[node];

        if (deg <= 64) {
            unsigned int pk = 0;
            float ev = -3.4e38f;
            const bool has = lane < deg;
            if (has) {
                pk = edge_list[beg + lane];
                ev = s1[pk & 0xFFFFu] + s2n;
                ev = ev > 0.f ? ev : 0.01f * ev;
            }
            float m = ev;
#pragma unroll
            for (int off = 32; off > 0; off >>= 1)
                m = fmaxf(m, __shfl_xor(m, off));
            float p = has ? __expf(ev - m) : 0.f;
            float den = p;
#pragma unroll
            for (int off = 32; off > 0; off >>= 1)
                den += __shfl_xor(den, off);
            const float inv = 1.f / den;
            if (has)
                lds_ws[wv][lane] = make_uint2(pk & 0xFFFFu,
                                              __float_as_uint(rel_emb[pk >> 16] * p * inv));
#pragma unroll 2
            for (int j = quad; j < deg; j += 4) {
                uint2 t = lds_ws[wv][j];
                float w = __uint_as_float(t.y);
                uint4 zv = z4[(size_t)t.x * 16 + q];
                const __half* hp = reinterpret_cast<const __half*>(&zv);
#pragma unroll
                for (int k2 = 0; k2 < 8; ++k2)
                    acc[k2] += w * __half2float(hp[k2]);
            }
        } else {
            float mymax = -3.4e38f;
            for (int k = beg + lane; k < end; k += 64) {
                unsigned int pk = edge_list[k];
                float ev = s1[pk & 0xFFFFu] + s2n;
                ev = ev > 0.f ? ev : 0.01f * ev;
                mymax = fmaxf(mymax, ev);
            }
#pragma unroll
            for (int off = 32; off > 0; off >>= 1)
                mymax = fmaxf(mymax, __shfl_xor(mymax, off));
            float mysum = 0.f;
            for (int k = beg + lane; k < end; k += 64) {
                unsigned int pk = edge_list[k];
                float ev = s1[pk & 0xFFFFu] + s2n;
                ev = ev > 0.f ? ev : 0.01f * ev;
                mysum += __expf(ev - mymax);
            }
#pragma unroll
            for (int off = 32; off > 0; off >>= 1)
                mysum += __shfl_xor(mysum, off);
            const float inv = 1.f / mysum;

            for (int cb = beg; cb < end; cb += 64) {
                int k = cb + lane;
                if (k < end) {
                    unsigned int pk = edge_list[k];
                    int s = pk & 0xFFFFu;
                    float ev = s1[s] + s2n;
                    ev = ev > 0.f ? ev : 0.01f * ev;
                    lds_ws[wv][lane] = make_uint2((unsigned)s,
                        __float_as_uint(rel_emb[pk >> 16] * __expf(ev - mymax) * inv));
                }
                int cnt = min(64, end - cb);
#pragma unroll 2
                for (int j = quad; j < cnt; j += 4) {
                    uint2 t = lds_ws[wv][j];
                    float w = __uint_as_float(t.y);
                    uint4 zv = z4[(size_t)t.x * 16 + q];
                    const __half* hp = reinterpret_cast<const __half*>(&zv);
#pragma unroll
                    for (int k2 = 0; k2 < 8; ++k2)
                        acc[k2] += w * __half2float(hp[k2]);
                }
            }
        }
        // reduce across the 4 quads
#pragma unroll
        for (int j = 0; j < 8; ++j) {
            acc[j] += __shfl_xor(acc[j], 16);
            acc[j] += __shfl_xor(acc[j], 32);
        }
    }

    if (quad == 0) {
        const float4* b4 = reinterpret_cast<const float4*>(bias);
        float4 b0 = b4[q * 2], b1 = b4[q * 2 + 1];
        float4* o4 = reinterpret_cast<float4*>(out);
        o4[(size_t)node * 32 + q * 2] =
            make_float4(acc[0] + b0.x, acc[1] + b0.y, acc[2] + b0.z, acc[3] + b0.w);
        o4[(size_t)node * 32 + q * 2 + 1] =
            make_float4(acc[4] + b1.x, acc[5] + b1.y, acc[6] + b1.z, acc[7] + b1.w);
    }
}

extern "C" void kernel_launch(void* const* d_in, const int* in_sizes, int n_in,
                              void* d_out, int out_size, void* d_ws, size_t ws_size,
                              hipStream_t stream) {
    const float* h      = (const float*)d_in[0];
    const float* W      = (const float*)d_in[1];
    const float* attn_w = (const float*)d_in[2];
    const float* rel    = (const float*)d_in[3];
    const float* bias   = (const float*)d_in[4];
    const int*   src    = (const int*)d_in[5];
    const int*   dst    = (const int*)d_in[6];
    const int*   etype  = (const int*)d_in[7];
    const int n = in_sizes[0] / NFEAT;   // 50000
    const int e = in_sizes[5];           // 1600000
    const int nbuk = (n + 63) / 64;      // 782
    const int epb = (e + HB - 1) / HB;   // 6250
    float* out = (float*)d_out;

    // workspace layout
    char* p = (char*)d_ws;
    __half* zh = (__half*)p;               p += (size_t)n * NFEAT * 2;
    float* s1 = (float*)p;                 p += (size_t)n * 4;
    float* s2 = (float*)p;                 p += (size_t)n * 4;
    float* Wt = (float*)p;                 p += (size_t)NFEAT * NFEAT * 4;
    int* row_start = (int*)p;              p += (size_t)(n + 1) * 4;
    int* hist       = (int*)p;             p += (size_t)HB * nbuk * 4;
    int* base       = (int*)p;             p += (size_t)HB * nbuk * 4;
    int* bucket_tot = (int*)p;             p += (size_t)nbuk * 4;
    int* bucket_base= (int*)p;             p += (size_t)nbuk * 4;
    unsigned int* edge_list    = (unsigned int*)p;  p += (size_t)e * 4;
    unsigned int* bucket_store = (unsigned int*)p;  p += (size_t)e * 4;

    k_transpose<<<(NFEAT * NFEAT + 255) / 256, 256, 0, stream>>>(W, Wt);
    k_gemm<<<(n + 31) / 32, 256, 0, stream>>>(h, Wt, attn_w, zh, s1, s2, n);
    k_hist<<<HB, 256, 0, stream>>>(dst, hist, e, nbuk, epb);
    k_scan_blocks<<<nbuk, 256, 0, stream>>>(hist, base, bucket_tot, nbuk);
    k_scan_buckets<<<1, 256, 0, stream>>>(bucket_tot, bucket_base, row_start, n, nbuk);
    k_sctr<<<HB, 256, 0, stream>>>(src, dst, etype, base, bucket_base, bucket_store, e, nbuk, epb);
    k_place<<<nbuk, 256, 0, stream>>>(bucket_store, bucket_tot, bucket_base, row_start, edge_list, n);
    k_aggregate<<<(n + 3) / 4, 256, 0, stream>>>(zh, s1, s2, rel, bias, row_start, edge_list, out, n);
}

// Round 6
// 143.706 us; speedup vs baseline: 3.8119x; 1.0277x over previous
//
#include <hip/hip_runtime.h>
#include <hip/hip_fp16.h>

#define NFEAT 128
#define NBUK_MAX 1024   // actual buckets = ceil(50000/64) = 782
#define HB 256          // blocks for hist/scatter passes
#define BCAP_L 4096     // k_place LDS edge capacity (mean 2046, sigma ~45)

// ---------- Wt[k][j] = W[j][k] (64 KB) ----------
__global__ void k_transpose(const float* __restrict__ W, float* __restrict__ Wt) {
    int i = blockIdx.x * 256 + threadIdx.x;
    if (i < NFEAT * NFEAT) {
        int r = i >> 7, c = i & 127;
        Wt[c * NFEAT + r] = W[i];
    }
}

// ---------- z(fp16) = h @ W^T, s1 = z.w1, s2 = z.w2 (scores from fp32 acc) ----------
__global__ __launch_bounds__(256) void k_gemm(
    const float* __restrict__ h, const float* __restrict__ Wt,
    const float* __restrict__ attn_w,
    __half* __restrict__ zh, float* __restrict__ s1, float* __restrict__ s2, int n)
{
    __shared__ float hs[32][NFEAT];
    const int tid = threadIdx.x;
    const int cg = tid & 31;
    const int rg = tid >> 5;
    const int nodeBase = blockIdx.x * 32;

    const float4* h4 = reinterpret_cast<const float4*>(h);
    float4* hs4 = reinterpret_cast<float4*>(&hs[0][0]);
    for (int t = tid; t < 32 * 32; t += 256) {
        int row = t >> 5, c4 = t & 31;
        int nn = nodeBase + row;
        hs4[t] = (nn < n) ? h4[(size_t)nn * 32 + c4] : make_float4(0.f, 0.f, 0.f, 0.f);
    }
    __syncthreads();

    const float4* Wt4 = reinterpret_cast<const float4*>(Wt);
    float acc[4][4];
#pragma unroll
    for (int r = 0; r < 4; ++r)
#pragma unroll
        for (int c = 0; c < 4; ++c) acc[r][c] = 0.f;

    for (int k0 = 0; k0 < NFEAT; k0 += 4) {
        float4 wv[4];
#pragma unroll
        for (int i = 0; i < 4; ++i) wv[i] = Wt4[(size_t)(k0 + i) * 32 + cg];
        float4 hv[4];
#pragma unroll
        for (int r = 0; r < 4; ++r)
            hv[r] = *reinterpret_cast<const float4*>(&hs[rg * 4 + r][k0]);
#pragma unroll
        for (int r = 0; r < 4; ++r) {
            float hk;
#pragma unroll
            for (int i = 0; i < 4; ++i) {
                hk = (i == 0) ? hv[r].x : (i == 1) ? hv[r].y : (i == 2) ? hv[r].z : hv[r].w;
                acc[r][0] += hk * wv[i].x;
                acc[r][1] += hk * wv[i].y;
                acc[r][2] += hk * wv[i].z;
                acc[r][3] += hk * wv[i].w;
            }
        }
    }

    const float4 aw1 = reinterpret_cast<const float4*>(attn_w)[cg];
    const float4 aw2 = reinterpret_cast<const float4*>(attn_w)[cg + 32];
    uint2* zh2 = reinterpret_cast<uint2*>(zh);

#pragma unroll
    for (int r = 0; r < 4; ++r) {
        int node = nodeBase + rg * 4 + r;
        bool valid = node < n;
        if (valid) {
            __half2 a01 = __floats2half2_rn(acc[r][0], acc[r][1]);
            __half2 a23 = __floats2half2_rn(acc[r][2], acc[r][3]);
            uint2 pk;
            pk.x = *reinterpret_cast<unsigned*>(&a01);
            pk.y = *reinterpret_cast<unsigned*>(&a23);
            zh2[(size_t)node * 32 + cg] = pk;
        }
        float p1 = acc[r][0] * aw1.x + acc[r][1] * aw1.y + acc[r][2] * aw1.z + acc[r][3] * aw1.w;
        float p2 = acc[r][0] * aw2.x + acc[r][1] * aw2.y + acc[r][2] * aw2.z + acc[r][3] * aw2.w;
#pragma unroll
        for (int off = 16; off > 0; off >>= 1) {
            p1 += __shfl_xor(p1, off);
            p2 += __shfl_xor(p2, off);
        }
        if (cg == 0 && valid) { s1[node] = p1; s2[node] = p2; }
    }
}

// ---------- pass 1: per-block LDS histogram over coarse buckets ----------
__global__ __launch_bounds__(256) void k_hist(const int* __restrict__ dst,
                                              int* __restrict__ hist,
                                              int e, int nbuk, int epb)
{
    __shared__ int lh[NBUK_MAX];
    const int b = blockIdx.x, tid = threadIdx.x;
    for (int k = tid; k < nbuk; k += 256) lh[k] = 0;
    __syncthreads();
    const int beg = b * epb, end = min(e, beg + epb);
    for (int i = beg + tid; i < end; i += 256)
        atomicAdd(&lh[dst[i] >> 6], 1);
    __syncthreads();
    for (int k = tid; k < nbuk; k += 256)
        hist[b * nbuk + k] = lh[k];
}

// ---------- pass 2a: per-bucket exclusive scan over blocks ----------
__global__ __launch_bounds__(256) void k_scan_blocks(const int* __restrict__ hist,
                                                     int* __restrict__ base,
                                                     int* __restrict__ bucket_tot, int nbuk)
{
    __shared__ int wsum[4];
    const int k = blockIdx.x, tid = threadIdx.x;
    int v = hist[tid * nbuk + k];
    int lane = tid & 63, wave = tid >> 6;
    int x = v;
#pragma unroll
    for (int off = 1; off < 64; off <<= 1) {
        int t = __shfl_up(x, off);
        if (lane >= off) x += t;
    }
    if (lane == 63) wsum[wave] = x;
    __syncthreads();
    int wb = 0;
    for (int w = 0; w < wave; ++w) wb += wsum[w];
    base[tid * nbuk + k] = wb + x - v;
    if (tid == 255) bucket_tot[k] = wb + x;
}

// ---------- pass 2b: exclusive scan of bucket totals (single block) ----------
__global__ __launch_bounds__(256) void k_scan_buckets(const int* __restrict__ bucket_tot,
                                                      int* __restrict__ bucket_base,
                                                      int* __restrict__ row_start,
                                                      int n, int nbuk)
{
    __shared__ int wsum[4];
    const int tid = threadIdx.x;
    const int C = (nbuk + 255) / 256;   // <= 4
    const int base_i = tid * C;
    int vals[8];
    int s = 0;
#pragma unroll
    for (int j = 0; j < 8; ++j) {
        int v = 0;
        if (j < C) {
            int idx = base_i + j;
            if (idx < nbuk) v = bucket_tot[idx];
        }
        vals[j] = v; s += v;
    }
    int lane = tid & 63, wave = tid >> 6;
    int x = s;
#pragma unroll
    for (int off = 1; off < 64; off <<= 1) {
        int t = __shfl_up(x, off);
        if (lane >= off) x += t;
    }
    if (lane == 63) wsum[wave] = x;
    __syncthreads();
    int wb = 0;
    for (int w = 0; w < wave; ++w) wb += wsum[w];
    int ex = wb + x - s;
#pragma unroll
    for (int j = 0; j < 8; ++j) {
        if (j < C) {
            int idx = base_i + j;
            if (idx < nbuk) bucket_base[idx] = ex;
            ex += vals[j];
        }
    }
    if (tid == 255) row_start[n] = ex;   // == e
}

// ---------- pass 3: deterministic scatter into coarse-sorted store ----------
// packed word: (dst&63)<<22 | etype<<16 | src
__global__ __launch_bounds__(256) void k_sctr(
    const int* __restrict__ src, const int* __restrict__ dst, const int* __restrict__ etype,
    const int* __restrict__ base, const int* __restrict__ bucket_base,
    unsigned int* __restrict__ bucket_store, int e, int nbuk, int epb)
{
    __shared__ int cur[NBUK_MAX];
    const int b = blockIdx.x, tid = threadIdx.x;
    for (int k = tid; k < nbuk; k += 256)
        cur[k] = base[b * nbuk + k] + bucket_base[k];
    __syncthreads();
    const int beg = b * epb, end = min(e, beg + epb);
    for (int i = beg + tid; i < end; i += 256) {
        int d = dst[i];
        int pos = atomicAdd(&cur[d >> 6], 1);
        bucket_store[pos] =
            (unsigned int)src[i] | ((unsigned int)etype[i] << 16) | ((unsigned int)(d & 63) << 22);
    }
}

// ---------- pass 4: per-bucket local sort -> CSR + row_start ----------
__global__ __launch_bounds__(256) void k_place(
    const unsigned int* __restrict__ bucket_store, const int* __restrict__ bucket_tot,
    const int* __restrict__ bucket_base,
    int* __restrict__ row_start, unsigned int* __restrict__ edge_list, int n)
{
    __shared__ unsigned int est[BCAP_L];
    __shared__ int cnt64[64];
    const int b = blockIdx.x;
    const int tid = threadIdx.x;
    const int cnt = min(bucket_tot[b], BCAP_L);
    const int base = bucket_base[b];

    if (tid < 64) cnt64[tid] = 0;
    for (int j = tid; j < cnt; j += 256)
        est[j] = bucket_store[(size_t)base + j];
    __syncthreads();
    for (int j = tid; j < cnt; j += 256)
        atomicAdd(&cnt64[est[j] >> 22], 1);
    __syncthreads();
    if (tid < 64) {
        int v = cnt64[tid];
        int x = v;
#pragma unroll
        for (int off = 1; off < 64; off <<= 1) {
            int t = __shfl_up(x, off);
            if (tid >= off) x += t;
        }
        int node = (b << 6) + tid;
        if (node < n) row_start[node] = base + x - v;
        cnt64[tid] = x - v;
    }
    __syncthreads();
    for (int j = tid; j < cnt; j += 256) {
        unsigned int pk = est[j];
        int pos = base + atomicAdd(&cnt64[pk >> 22], 1);
        edge_list[pos] = pk & 0x3FFFFFu;
    }
}

// ---------- per-node softmax + weighted aggregation; 1 wave = 1 node ----------
// fast path: edge metadata lives in registers, broadcast via shfl; gather is
// 4-way unrolled (16 edges / 4 independent uint4 loads in flight per iter).
__global__ __launch_bounds__(256) void k_aggregate(
    const __half* __restrict__ zh, const float* __restrict__ s1, const float* __restrict__ s2,
    const float* __restrict__ rel_emb, const float* __restrict__ bias,
    const int* __restrict__ row_start, const unsigned int* __restrict__ edge_list,
    float* __restrict__ out, int n)
{
    __shared__ uint2 lds_ws[4][64];   // rare path only
    const int wv   = threadIdx.x >> 6;
    const int lane = threadIdx.x & 63;
    const int node = blockIdx.x * 4 + wv;
    if (node >= n) return;

    const int beg = row_start[node];
    const int end = row_start[node + 1];
    const int deg = end - beg;
    const int quad = lane >> 4;   // which edge of the group of 4
    const int q    = lane & 15;   // 8-half chunk within the 128-feat row

    float acc[8];
#pragma unroll
    for (int j = 0; j < 8; ++j) acc[j] = 0.f;
    const uint4* z4 = reinterpret_cast<const uint4*>(zh);

    if (deg > 0) {
        const float s2n = s2[node];

        if (deg <= 64) {
            unsigned int pk = 0;
            float ev = -3.4e38f;
            const bool has = lane < deg;
            if (has) {
                pk = edge_list[beg + lane];
                ev = s1[pk & 0xFFFFu] + s2n;
                ev = ev > 0.f ? ev : 0.01f * ev;
            }
            float m = ev;
#pragma unroll
            for (int off = 32; off > 0; off >>= 1)
                m = fmaxf(m, __shfl_xor(m, off));
            float p = has ? __expf(ev - m) : 0.f;
            float den = p;
#pragma unroll
            for (int off = 32; off > 0; off >>= 1)
                den += __shfl_xor(den, off);
            const float inv = 1.f / den;
            const int   src_i = has ? (int)(pk & 0xFFFFu) : 0;
            const float wgt   = has ? rel_emb[pk >> 16] * p * inv : 0.f;

            int jb = 0;
            for (; jb + 16 <= deg; jb += 16) {
                const int j0 = jb + quad;
                int   sA = __shfl(src_i, j0),      sB = __shfl(src_i, j0 + 4);
                int   sC = __shfl(src_i, j0 + 8),  sD = __shfl(src_i, j0 + 12);
                float wA = __shfl(wgt, j0),        wB = __shfl(wgt, j0 + 4);
                float wC = __shfl(wgt, j0 + 8),    wD = __shfl(wgt, j0 + 12);
                uint4 vA = z4[(size_t)sA * 16 + q];
                uint4 vB = z4[(size_t)sB * 16 + q];
                uint4 vC = z4[(size_t)sC * 16 + q];
                uint4 vD = z4[(size_t)sD * 16 + q];
                const __half* hA = reinterpret_cast<const __half*>(&vA);
                const __half* hB = reinterpret_cast<const __half*>(&vB);
                const __half* hC = reinterpret_cast<const __half*>(&vC);
                const __half* hD = reinterpret_cast<const __half*>(&vD);
#pragma unroll
                for (int k2 = 0; k2 < 8; ++k2) {
                    acc[k2] += wA * __half2float(hA[k2]);
                    acc[k2] += wB * __half2float(hB[k2]);
                    acc[k2] += wC * __half2float(hC[k2]);
                    acc[k2] += wD * __half2float(hD[k2]);
                }
            }
            for (; jb < deg; jb += 4) {
                const int j = jb + quad;        // j <= 63 always; w=0 if j >= deg
                int   sj = __shfl(src_i, j);
                float wj = __shfl(wgt, j);
                uint4 zv = z4[(size_t)sj * 16 + q];
                const __half* hp = reinterpret_cast<const __half*>(&zv);
#pragma unroll
                for (int k2 = 0; k2 < 8; ++k2)
                    acc[k2] += wj * __half2float(hp[k2]);
            }
        } else {
            // ---- rare path: degree > 64, chunked via LDS
            float mymax = -3.4e38f;
            for (int k = beg + lane; k < end; k += 64) {
                unsigned int pk = edge_list[k];
                float ev = s1[pk & 0xFFFFu] + s2n;
                ev = ev > 0.f ? ev : 0.01f * ev;
                mymax = fmaxf(mymax, ev);
            }
#pragma unroll
            for (int off = 32; off > 0; off >>= 1)
                mymax = fmaxf(mymax, __shfl_xor(mymax, off));
            float mysum = 0.f;
            for (int k = beg + lane; k < end; k += 64) {
                unsigned int pk = edge_list[k];
                float ev = s1[pk & 0xFFFFu] + s2n;
                ev = ev > 0.f ? ev : 0.01f * ev;
                mysum += __expf(ev - mymax);
            }
#pragma unroll
            for (int off = 32; off > 0; off >>= 1)
                mysum += __shfl_xor(mysum, off);
            const float inv = 1.f / mysum;

            for (int cb = beg; cb < end; cb += 64) {
                int k = cb + lane;
                if (k < end) {
                    unsigned int pk = edge_list[k];
                    int s = pk & 0xFFFFu;
                    float ev = s1[s] + s2n;
                    ev = ev > 0.f ? ev : 0.01f * ev;
                    lds_ws[wv][lane] = make_uint2((unsigned)s,
                        __float_as_uint(rel_emb[pk >> 16] * __expf(ev - mymax) * inv));
                }
                int cnt = min(64, end - cb);
#pragma unroll 2
                for (int j = quad; j < cnt; j += 4) {
                    uint2 t = lds_ws[wv][j];
                    float w = __uint_as_float(t.y);
                    uint4 zv = z4[(size_t)t.x * 16 + q];
                    const __half* hp = reinterpret_cast<const __half*>(&zv);
#pragma unroll
                    for (int k2 = 0; k2 < 8; ++k2)
                        acc[k2] += w * __half2float(hp[k2]);
                }
            }
        }
        // reduce across the 4 quads
#pragma unroll
        for (int j = 0; j < 8; ++j) {
            acc[j] += __shfl_xor(acc[j], 16);
            acc[j] += __shfl_xor(acc[j], 32);
        }
    }

    if (quad == 0) {
        const float4* b4 = reinterpret_cast<const float4*>(bias);
        float4 b0 = b4[q * 2], b1 = b4[q * 2 + 1];
        float4* o4 = reinterpret_cast<float4*>(out);
        o4[(size_t)node * 32 + q * 2] =
            make_float4(acc[0] + b0.x, acc[1] + b0.y, acc[2] + b0.z, acc[3] + b0.w);
        o4[(size_t)node * 32 + q * 2 + 1] =
            make_float4(acc[4] + b1.x, acc[5] + b1.y, acc[6] + b1.z, acc[7] + b1.w);
    }
}

extern "C" void kernel_launch(void* const* d_in, const int* in_sizes, int n_in,
                              void* d_out, int out_size, void* d_ws, size_t ws_size,
                              hipStream_t stream) {
    const float* h      = (const float*)d_in[0];
    const float* W      = (const float*)d_in[1];
    const float* attn_w = (const float*)d_in[2];
    const float* rel    = (const float*)d_in[3];
    const float* bias   = (const float*)d_in[4];
    const int*   src    = (const int*)d_in[5];
    const int*   dst    = (const int*)d_in[6];
    const int*   etype  = (const int*)d_in[7];
    const int n = in_sizes[0] / NFEAT;   // 50000
    const int e = in_sizes[5];           // 1600000
    const int nbuk = (n + 63) / 64;      // 782
    const int epb = (e + HB - 1) / HB;   // 6250
    float* out = (float*)d_out;

    // workspace layout
    char* p = (char*)d_ws;
    __half* zh = (__half*)p;               p += (size_t)n * NFEAT * 2;
    float* s1 = (float*)p;                 p += (size_t)n * 4;
    float* s2 = (float*)p;                 p += (size_t)n * 4;
    float* Wt = (float*)p;                 p += (size_t)NFEAT * NFEAT * 4;
    int* row_start = (int*)p;              p += (size_t)(n + 1) * 4;
    int* hist       = (int*)p;             p += (size_t)HB * nbuk * 4;
    int* base       = (int*)p;             p += (size_t)HB * nbuk * 4;
    int* bucket_tot = (int*)p;             p += (size_t)nbuk * 4;
    int* bucket_base= (int*)p;             p += (size_t)nbuk * 4;
    unsigned int* edge_list    = (unsigned int*)p;  p += (size_t)e * 4;
    unsigned int* bucket_store = (unsigned int*)p;  p += (size_t)e * 4;

    k_transpose<<<(NFEAT * NFEAT + 255) / 256, 256, 0, stream>>>(W, Wt);
    k_gemm<<<(n + 31) / 32, 256, 0, stream>>>(h, Wt, attn_w, zh, s1, s2, n);
    k_hist<<<HB, 256, 0, stream>>>(dst, hist, e, nbuk, epb);
    k_scan_blocks<<<nbuk, 256, 0, stream>>>(hist, base, bucket_tot, nbuk);
    k_scan_buckets<<<1, 256, 0, stream>>>(bucket_tot, bucket_base, row_start, n, nbuk);
    k_sctr<<<HB, 256, 0, stream>>>(src, dst, etype, base, bucket_base, bucket_store, e, nbuk, epb);
    k_place<<<nbuk, 256, 0, stream>>>(bucket_store, bucket_tot, bucket_base, row_start, edge_list, n);
    k_aggregate<<<(n + 3) / 4, 256, 0, stream>>>(zh, s1, s2, rel, bias, row_start, edge_list, out, n);
}